// Round 9
// baseline (1113.863 us; speedup 1.0000x reference)
//
#include <hip/hip_runtime.h>

// LSTM_26912265077001: 2-layer LSTM (H=51, IN=1), T=512, B=1024, fp32.
//
// V10: cut the per-step critical path (latency, not throughput, is the
// entire runtime: 512 serial steps x ~1.9us).
// V9 post-mortem: 3rd register intervention, identical counters ->
// B-frag residency never mattered. On ACTIVE CUs VALU~76%/MFMA~25% busy;
// issue model reconciles only at ~1000-1500 effective cy/iter -> the
// loop is stall/latency-bound (likely DVFS-throttled at 25% CU util).
// V10 changes (vs V9):
//  (1) NO VMEM in the loop: y results go to LDS ybuf (32KB), flushed
//      once at the end -> __syncthreads no longer drains vmcnt(0) of a
//      global store every iteration.
//  (2) MFMA dependency chains split: L1 = 3 independent 2-deep chains,
//      L2 = 8-deep (Bh) + 4-deep (Bl) chains, merged with vector adds
//      -> dependent-MFMA critical path ~halved.
//  (3) x pre-split to packed (hi,lo) u32 at init -> staging is 1 LDS
//      read + 2 u16 writes, no cvt math on wave 0's tail.
//  (4) wlin/blin in registers (no per-iter LDS reads for the y-dot).
// Everything else (roles, parities, gate-aligned tiles, 1 barrier/iter,
// prep kernel + packed weights) as V9.

#define Hs    51
#define Ts    512
#define Bs    1024
#define NB    16
#define NT    512
#define SA    136        // A row stride in ushorts (272B, 16B-aligned)
#define XCOL  51
#define H2COL 64

typedef __attribute__((ext_vector_type(8))) short bf16x8;
typedef __attribute__((ext_vector_type(4))) float f32x4;
typedef __attribute__((ext_vector_type(4))) int   i32x4;
typedef unsigned short u16;

__device__ __forceinline__ float sig_(float x)  { return 1.0f / (1.0f + __expf(-x)); }
__device__ __forceinline__ float tanh_(float x) { float e = __expf(2.0f * x); return 1.0f - 2.0f / (e + 1.0f); }
__device__ __forceinline__ u16 bfh_(float x) {   // fp32 -> bf16 (RNE)
    unsigned u = __float_as_uint(x);
    return (u16)((u + 0x7FFFu + ((u >> 16) & 1u)) >> 16);
}
__device__ __forceinline__ float bff_(u16 h) { return __uint_as_float(((unsigned)h) << 16); }

struct FragHL { bf16x8 h; bf16x8 l; };

// B1 fragment: row of [W_hh1 | W_ih1] at K-step ks, chunk ch.
__device__ __forceinline__ FragHL mkB1(const float* __restrict__ Whh1,
                                       const float* __restrict__ Wih1,
                                       int row, bool rv, int ks, int ch) {
    bf16x8 h = {0,0,0,0,0,0,0,0}, l = {0,0,0,0,0,0,0,0};
    #pragma unroll
    for (int j = 0; j < 8; ++j) {
        const int k = ks * 32 + ch * 8 + j;
        float v = 0.f;
        if (rv) {
            if (k < Hs)         v = Whh1[row * Hs + k];
            else if (k == XCOL) v = Wih1[row];
        }
        u16 hh = bfh_(v);
        h[j] = (short)hh;
        l[j] = (short)bfh_(v - bff_(hh));
    }
    FragHL r; r.h = h; r.l = l; return r;
}

// B2 fragment: row of [W_ih2 | 0 | W_hh2 | 0] at K-step ks, chunk ch.
__device__ __forceinline__ FragHL mkB2(const float* __restrict__ Wih2,
                                       const float* __restrict__ Whh2,
                                       int row, bool rv, int ks, int ch) {
    bf16x8 h = {0,0,0,0,0,0,0,0}, l = {0,0,0,0,0,0,0,0};
    #pragma unroll
    for (int j = 0; j < 8; ++j) {
        const int k = ks * 32 + ch * 8 + j;
        float v = 0.f;
        if (rv) {
            if (k < Hs)                              v = Wih2[row * Hs + k];
            else if (k >= H2COL && k < H2COL + Hs)   v = Whh2[row * Hs + (k - H2COL)];
        }
        u16 hh = bfh_(v);
        h[j] = (short)hh;
        l[j] = (short)bfh_(v - bff_(hh));
    }
    FragHL r; r.h = h; r.l = l; return r;
}

// ---- packed weight store: [tid][32 frag slots][8 u16] + fused biases ----
__device__ __align__(16) u16   g_pack[NT * 32 * 8];   // 256 KB
__device__ __align__(16) float g_bias[NT * 4];

__global__ __launch_bounds__(NT) void prep_kernel(
    const float* __restrict__ W_ih1, const float* __restrict__ W_hh1,
    const float* __restrict__ b_ih1, const float* __restrict__ b_hh1,
    const float* __restrict__ W_ih2, const float* __restrict__ W_hh2,
    const float* __restrict__ b_ih2, const float* __restrict__ b_hh2)
{
    const int tid  = threadIdx.x;
    const int lane = tid & 63;
    const int wv   = tid >> 6;
    const int role = wv >> 2;
    const int jg   = wv & 3;
    const int m    = lane & 15;
    const int ch   = lane >> 4;
    const int jrow = jg * 16 + m;
    const bool rv  = jrow < Hs;
    const int nks  = role ? 4 : 2;
    u16* base = &g_pack[tid * 256];

    for (int g = 0; g < 4; ++g) {
        const int row = g * Hs + jrow;
        g_bias[tid * 4 + g] = rv ? (role ? (b_ih2[row] + b_hh2[row])
                                         : (b_ih1[row] + b_hh1[row]))
                                 : 0.f;
        for (int s = 0; s < nks; ++s) {
            FragHL f = role ? mkB2(W_ih2, W_hh2, row, rv, s, ch)
                            : mkB1(W_hh1, W_ih1, row, rv, s, ch);
            *(bf16x8*)(base + (g * (2 * nks) + 2 * s + 0) * 8) = f.h;
            *(bf16x8*)(base + (g * (2 * nks) + 2 * s + 1) * 8) = f.l;
        }
    }
}

// opaque fragment load: value cannot be rematerialized by the compiler
__device__ __forceinline__ bf16x8 ldfrag(const u16* p) {
    i32x4 v = *(const i32x4*)p;
    asm volatile("" : "+v"(v));
    union { i32x4 i; bf16x8 b; } u;
    u.i = v;
    return u.b;
}

#define MFMA_(A, B, C) __builtin_amdgcn_mfma_f32_16x16x32_bf16(A, B, C, 0, 0, 0)

__global__ __launch_bounds__(NT)
void lstm2_kernel(
    const float* __restrict__ x,      // (T, B, 1)
    const float* __restrict__ W_lin,  // (1, 51)
    const float* __restrict__ b_lin,  // (1,)
    float* __restrict__ out)          // (B, T)
{
    __shared__ __align__(16) u16      Ah[2][NB * SA];
    __shared__ __align__(16) u16      Al[2][NB * SA];
    __shared__ __align__(16) unsigned xs32[Ts][NB];    // packed (hi,lo) x
    __shared__ __align__(16) float    h2f[2][NB][68];
    __shared__ __align__(16) float    ybuf[NB][Ts];    // 32 KB output buffer
    __shared__ __align__(16) float    wlin_s[64];
    __shared__ float blin_sh;

    const int tid  = threadIdx.x;
    const int lane = tid & 63;
    const int wv   = tid >> 6;         // 0..7
    const int role = wv >> 2;          // 0 = L1, 1 = L2
    const int jg   = wv & 3;
    const int m    = lane & 15;
    const int ch   = lane >> 4;
    const int bg0  = blockIdx.x * NB;
    const int  jrow = jg * 16 + m;     // unit index (valid < 51)
    const bool rv   = jrow < Hs;

    // ---- one-time init: zero / preload (NO staging writes yet) ----
    for (int i = tid; i < Ts * NB; i += NT) {
        int t = i >> 4, b = i & 15;
        float xv = x[t * Bs + bg0 + b];
        u16 hh = bfh_(xv);
        u16 hl = bfh_(xv - bff_(hh));
        xs32[t][b] = (unsigned)hh | ((unsigned)hl << 16);
    }
    for (int i = tid; i < 2 * NB * SA; i += NT) {
        ((u16*)Ah)[i] = 0;
        ((u16*)Al)[i] = 0;
    }
    for (int i = tid; i < 2 * NB * 68; i += NT) ((float*)h2f)[i] = 0.f;
    if (tid < 64) wlin_s[tid] = (tid < Hs) ? W_lin[tid] : 0.f;
    if (tid == 0) blin_sh = b_lin[0];
    __syncthreads();                   // zero-fill visible first (V7 race fix)

    if (tid < NB) {                    // x[0] into parity 1 (read at it=0)
        unsigned v = xs32[0][tid];
        Ah[1][tid * SA + XCOL] = (u16)v;
        Al[1][tid * SA + XCOL] = (u16)(v >> 16);
    }

    // ---- biases: opaque register load ----
    f32x4 bb4 = *(const f32x4*)&g_bias[tid * 4];
    asm volatile("" : "+v"(bb4));
    const float bbI = bb4.x, bbF = bb4.y, bbG = bb4.z, bbO = bb4.w;

    const u16* pk = &g_pack[tid * 256];

    float cc0 = 0.f, cc1 = 0.f, cc2 = 0.f, cc3 = 0.f;
    __syncthreads();                   // staging + wlin visible

    // hoist W_lin / b_lin into registers (constant across the loop)
    const float wl0 = wlin_s[m],      wl1 = wlin_s[m + 16];
    const float wl2 = wlin_s[m + 32], wl3 = wlin_s[m + 48];
    const float blin_r = blin_sh;

    if (role == 0) {
        // ======================= L1 path =======================
        bf16x8 bI0h = ldfrag(pk + (0*4 + 0)*8), bI0l = ldfrag(pk + (0*4 + 1)*8);
        bf16x8 bI1h = ldfrag(pk + (0*4 + 2)*8), bI1l = ldfrag(pk + (0*4 + 3)*8);
        bf16x8 bF0h = ldfrag(pk + (1*4 + 0)*8), bF0l = ldfrag(pk + (1*4 + 1)*8);
        bf16x8 bF1h = ldfrag(pk + (1*4 + 2)*8), bF1l = ldfrag(pk + (1*4 + 3)*8);
        bf16x8 bG0h = ldfrag(pk + (2*4 + 0)*8), bG0l = ldfrag(pk + (2*4 + 1)*8);
        bf16x8 bG1h = ldfrag(pk + (2*4 + 2)*8), bG1l = ldfrag(pk + (2*4 + 3)*8);
        bf16x8 bO0h = ldfrag(pk + (3*4 + 0)*8), bO0l = ldfrag(pk + (3*4 + 1)*8);
        bf16x8 bO1h = ldfrag(pk + (3*4 + 2)*8), bO1l = ldfrag(pk + (3*4 + 3)*8);

        for (int it = 0; it <= Ts + 1; ++it) {
            const int pR = (it - 1) & 1;
            const int pW = it & 1;
            if (it < Ts) {
                const u16* ph = &Ah[pR][m * SA + ch * 8];
                const u16* pl = &Al[pR][m * SA + ch * 8];
                bf16x8 A0h = *(const bf16x8*)(ph);
                bf16x8 A0l = *(const bf16x8*)(pl);
                bf16x8 A1h = *(const bf16x8*)(ph + 32);
                bf16x8 A1l = *(const bf16x8*)(pl + 32);
                // 3 independent 2-deep chains per gate, merged with adds
                #define L1GATE(OUT, BB, B0h, B0l, B1h, B1l)                    \
                {                                                              \
                    f32x4 p = {BB, BB, BB, BB};                                \
                    f32x4 q = {0.f, 0.f, 0.f, 0.f};                            \
                    f32x4 r = {0.f, 0.f, 0.f, 0.f};                            \
                    p = MFMA_(A0h, B0h, p); p = MFMA_(A1h, B1h, p);            \
                    q = MFMA_(A0l, B0h, q); q = MFMA_(A1l, B1h, q);            \
                    r = MFMA_(A0h, B0l, r); r = MFMA_(A1h, B1l, r);            \
                    OUT = (p + q) + r;                                         \
                }
                f32x4 aI, aF, aG, aO;
                L1GATE(aI, bbI, bI0h, bI0l, bI1h, bI1l)
                L1GATE(aF, bbF, bF0h, bF0l, bF1h, bF1l)
                L1GATE(aG, bbG, bG0h, bG0l, bG1h, bG1l)
                L1GATE(aO, bbO, bO0h, bO0l, bO1h, bO1l)
                #undef L1GATE
                #define E1STEP(RR, CC)                                         \
                {                                                              \
                    float iv = sig_ (aI[RR]);                                  \
                    float fv = sig_ (aF[RR]);                                  \
                    float gv = tanh_(aG[RR]);                                  \
                    float ov = sig_ (aO[RR]);                                  \
                    CC = fmaf(fv, CC, iv * gv);                                \
                    float hv = ov * tanh_(CC);                                 \
                    if (rv) {                                                  \
                        const int b = 4 * ch + RR;                             \
                        u16 hh = bfh_(hv);                                     \
                        Ah[pW][b * SA + jrow] = hh;                            \
                        Al[pW][b * SA + jrow] = bfh_(hv - bff_(hh));           \
                    }                                                          \
                }
                E1STEP(0, cc0) E1STEP(1, cc1) E1STEP(2, cc2) E1STEP(3, cc3)
                #undef E1STEP
            }
            // x[it+1] staging into parity pW (wave 0, 16 lanes; pre-split)
            if (jg == 0 && lane < NB && (it + 1) < Ts) {
                unsigned v = xs32[it + 1][lane];
                Ah[pW][lane * SA + XCOL] = (u16)v;
                Al[pW][lane * SA + XCOL] = (u16)(v >> 16);
            }
            // y[it-2] = W_lin . h2[it-2] + b -> LDS ybuf (NO global store)
            if (it >= 2) {
                const float* hp = &h2f[it & 1][4 * jg + ch][0];
                float s = wl0 * hp[m] + wl1 * hp[m + 16]
                        + wl2 * hp[m + 32] + wl3 * hp[m + 48];
                s += __shfl_xor(s, 1);
                s += __shfl_xor(s, 2);
                s += __shfl_xor(s, 4);
                s += __shfl_xor(s, 8);
                if (m == 0) ybuf[4 * jg + ch][it - 2] = s + blin_r;
            }
            __syncthreads();
        }
    } else {
        // ======================= L2 path =======================
        bf16x8 cI0h = ldfrag(pk + (0*8 + 0)*8), cI0l = ldfrag(pk + (0*8 + 1)*8);
        bf16x8 cI1h = ldfrag(pk + (0*8 + 2)*8), cI1l = ldfrag(pk + (0*8 + 3)*8);
        bf16x8 cI2h = ldfrag(pk + (0*8 + 4)*8), cI2l = ldfrag(pk + (0*8 + 5)*8);
        bf16x8 cI3h = ldfrag(pk + (0*8 + 6)*8), cI3l = ldfrag(pk + (0*8 + 7)*8);
        bf16x8 cF0h = ldfrag(pk + (1*8 + 0)*8), cF0l = ldfrag(pk + (1*8 + 1)*8);
        bf16x8 cF1h = ldfrag(pk + (1*8 + 2)*8), cF1l = ldfrag(pk + (1*8 + 3)*8);
        bf16x8 cF2h = ldfrag(pk + (1*8 + 4)*8), cF2l = ldfrag(pk + (1*8 + 5)*8);
        bf16x8 cF3h = ldfrag(pk + (1*8 + 6)*8), cF3l = ldfrag(pk + (1*8 + 7)*8);
        bf16x8 cG0h = ldfrag(pk + (2*8 + 0)*8), cG0l = ldfrag(pk + (2*8 + 1)*8);
        bf16x8 cG1h = ldfrag(pk + (2*8 + 2)*8), cG1l = ldfrag(pk + (2*8 + 3)*8);
        bf16x8 cG2h = ldfrag(pk + (2*8 + 4)*8), cG2l = ldfrag(pk + (2*8 + 5)*8);
        bf16x8 cG3h = ldfrag(pk + (2*8 + 6)*8), cG3l = ldfrag(pk + (2*8 + 7)*8);
        bf16x8 cO0h = ldfrag(pk + (3*8 + 0)*8), cO0l = ldfrag(pk + (3*8 + 1)*8);
        bf16x8 cO1h = ldfrag(pk + (3*8 + 2)*8), cO1l = ldfrag(pk + (3*8 + 3)*8);
        bf16x8 cO2h = ldfrag(pk + (3*8 + 4)*8), cO2l = ldfrag(pk + (3*8 + 5)*8);
        bf16x8 cO3h = ldfrag(pk + (3*8 + 6)*8), cO3l = ldfrag(pk + (3*8 + 7)*8);

        for (int it = 0; it <= Ts + 1; ++it) {
            const int pR = (it - 1) & 1;
            const int pW = it & 1;
            if (it >= 1 && it <= Ts) {
                const u16* ph = &Ah[pR][m * SA + ch * 8];
                const u16* pl = &Al[pR][m * SA + ch * 8];
                bf16x8 A0h = *(const bf16x8*)(ph);
                bf16x8 A0l = *(const bf16x8*)(pl);
                bf16x8 A1h = *(const bf16x8*)(ph + 32);
                bf16x8 A1l = *(const bf16x8*)(pl + 32);
                bf16x8 A2h = *(const bf16x8*)(ph + 64);
                bf16x8 A2l = *(const bf16x8*)(pl + 64);
                bf16x8 A3h = *(const bf16x8*)(ph + 96);
                bf16x8 A3l = *(const bf16x8*)(pl + 96);
                // 2 chains per gate: 8-deep (Bh terms) + 4-deep (Bl term)
                #define L2GATE(OUT, BB, C0h, C0l, C1h, C1l, C2h, C2l, C3h, C3l)\
                {                                                              \
                    f32x4 p = {BB, BB, BB, BB};                                \
                    f32x4 r = {0.f, 0.f, 0.f, 0.f};                            \
                    p = MFMA_(A0h, C0h, p); p = MFMA_(A1h, C1h, p);            \
                    p = MFMA_(A2h, C2h, p); p = MFMA_(A3h, C3h, p);            \
                    p = MFMA_(A0l, C0h, p); p = MFMA_(A1l, C1h, p);            \
                    p = MFMA_(A2l, C2h, p); p = MFMA_(A3l, C3h, p);            \
                    r = MFMA_(A0h, C0l, r); r = MFMA_(A1h, C1l, r);            \
                    r = MFMA_(A2h, C2l, r); r = MFMA_(A3h, C3l, r);            \
                    OUT = p + r;                                               \
                }
                f32x4 aI, aF, aG, aO;
                L2GATE(aI, bbI, cI0h, cI0l, cI1h, cI1l, cI2h, cI2l, cI3h, cI3l)
                L2GATE(aF, bbF, cF0h, cF0l, cF1h, cF1l, cF2h, cF2l, cF3h, cF3l)
                L2GATE(aG, bbG, cG0h, cG0l, cG1h, cG1l, cG2h, cG2l, cG3h, cG3l)
                L2GATE(aO, bbO, cO0h, cO0l, cO1h, cO1l, cO2h, cO2l, cO3h, cO3l)
                #undef L2GATE
                const int pE = (it - 1) & 1;     // h2f parity for h2[it-1]
                #define E2STEP(RR, CC)                                         \
                {                                                              \
                    float iv = sig_ (aI[RR]);                                  \
                    float fv = sig_ (aF[RR]);                                  \
                    float gv = tanh_(aG[RR]);                                  \
                    float ov = sig_ (aO[RR]);                                  \
                    CC = fmaf(fv, CC, iv * gv);                                \
                    float hv = ov * tanh_(CC);                                 \
                    if (rv) {                                                  \
                        const int b = 4 * ch + RR;                             \
                        u16 hh = bfh_(hv);                                     \
                        Ah[pW][b * SA + H2COL + jrow] = hh;                    \
                        Al[pW][b * SA + H2COL + jrow] = bfh_(hv - bff_(hh));   \
                        h2f[pE][b][jrow] = hv;                                 \
                    }                                                          \
                }
                E2STEP(0, cc0) E2STEP(1, cc1) E2STEP(2, cc2) E2STEP(3, cc3)
                #undef E2STEP
            }
            __syncthreads();
        }
    }

    // ---- single coalesced flush of the output buffer ----
    __syncthreads();
    for (int i = tid; i < NB * Ts; i += NT) {
        int b = i >> 9, t = i & (Ts - 1);
        out[(bg0 + b) * Ts + t] = ybuf[b][t];
    }
}

extern "C" void kernel_launch(void* const* d_in, const int* in_sizes, int n_in,
                              void* d_out, int out_size, void* d_ws, size_t ws_size,
                              hipStream_t stream) {
    const float* x     = (const float*)d_in[0];
    const float* W_ih1 = (const float*)d_in[1];
    const float* W_hh1 = (const float*)d_in[2];
    const float* b_ih1 = (const float*)d_in[3];
    const float* b_hh1 = (const float*)d_in[4];
    const float* W_ih2 = (const float*)d_in[5];
    const float* W_hh2 = (const float*)d_in[6];
    const float* b_ih2 = (const float*)d_in[7];
    const float* b_hh2 = (const float*)d_in[8];
    const float* W_lin = (const float*)d_in[9];
    const float* b_lin = (const float*)d_in[10];
    float* out = (float*)d_out;

    prep_kernel<<<1, NT, 0, stream>>>(W_ih1, W_hh1, b_ih1, b_hh1,
                                      W_ih2, W_hh2, b_ih2, b_hh2);
    lstm2_kernel<<<Bs / NB, NT, 0, stream>>>(x, W_lin, b_lin, out);
}

// Round 10
// 1101.340 us; speedup vs baseline: 1.0114x; 1.0114x over previous
//
#include <hip/hip_runtime.h>

// LSTM_26912265077001: 2-layer LSTM (H=51, IN=1), T=512, B=1024, fp32.
//
// V11: USE ALL 256 CUs (fix the DVFS down-clock).
// V10 post-mortem: 4 structurally different kernels all ran ~2us/iter at
// 64 blocks. MFMA-busy accounting: V4 (256 blocks) reconciles at 2.4GHz;
// V9/V10 (64 blocks) reconcile only at ~600-700MHz -> with 25% of CUs
// active the chip runs at ~1/4 clock. Every intra-kernel optimization
// since V5 was fighting a down-clocked part.
// V11 = V10 with NB=4, grid=256 blocks (1 block/CU):
//  - MFMA M-dim 4/16 used (irrelevant: latency-bound, per-CU FLOPs
//    unchanged, B spread over 4x more CUs).
//  - A-tile keeps 16 zero-padded rows so fragment reads stay in-bounds;
//    only rows 0-3 written. E-steps / h-writebacks guarded to ch==0
//    (batches 0-3 live in accumulator rows 0-3 = ch0's 4 regs).
//  - y-dot: L1 wave jg handles batch jg (ch groups redundant, lane 0
//    writes). All V10 improvements retained: no VMEM in loop (ybuf),
//    split MFMA chains, pre-split x, register wlin/blin.

#define Hs    51
#define Ts    512
#define Bs    1024
#define NB    4          // real batches per block (256 blocks)
#define NBA   16         // A-tile rows (zero-padded to MFMA M)
#define NT    512
#define SA    136        // A row stride in ushorts (272B, 16B-aligned)
#define XCOL  51
#define H2COL 64

typedef __attribute__((ext_vector_type(8))) short bf16x8;
typedef __attribute__((ext_vector_type(4))) float f32x4;
typedef __attribute__((ext_vector_type(4))) int   i32x4;
typedef unsigned short u16;

__device__ __forceinline__ float sig_(float x)  { return 1.0f / (1.0f + __expf(-x)); }
__device__ __forceinline__ float tanh_(float x) { float e = __expf(2.0f * x); return 1.0f - 2.0f / (e + 1.0f); }
__device__ __forceinline__ u16 bfh_(float x) {   // fp32 -> bf16 (RNE)
    unsigned u = __float_as_uint(x);
    return (u16)((u + 0x7FFFu + ((u >> 16) & 1u)) >> 16);
}
__device__ __forceinline__ float bff_(u16 h) { return __uint_as_float(((unsigned)h) << 16); }

struct FragHL { bf16x8 h; bf16x8 l; };

// B1 fragment: row of [W_hh1 | W_ih1] at K-step ks, chunk ch.
__device__ __forceinline__ FragHL mkB1(const float* __restrict__ Whh1,
                                       const float* __restrict__ Wih1,
                                       int row, bool rv, int ks, int ch) {
    bf16x8 h = {0,0,0,0,0,0,0,0}, l = {0,0,0,0,0,0,0,0};
    #pragma unroll
    for (int j = 0; j < 8; ++j) {
        const int k = ks * 32 + ch * 8 + j;
        float v = 0.f;
        if (rv) {
            if (k < Hs)         v = Whh1[row * Hs + k];
            else if (k == XCOL) v = Wih1[row];
        }
        u16 hh = bfh_(v);
        h[j] = (short)hh;
        l[j] = (short)bfh_(v - bff_(hh));
    }
    FragHL r; r.h = h; r.l = l; return r;
}

// B2 fragment: row of [W_ih2 | 0 | W_hh2 | 0] at K-step ks, chunk ch.
__device__ __forceinline__ FragHL mkB2(const float* __restrict__ Wih2,
                                       const float* __restrict__ Whh2,
                                       int row, bool rv, int ks, int ch) {
    bf16x8 h = {0,0,0,0,0,0,0,0}, l = {0,0,0,0,0,0,0,0};
    #pragma unroll
    for (int j = 0; j < 8; ++j) {
        const int k = ks * 32 + ch * 8 + j;
        float v = 0.f;
        if (rv) {
            if (k < Hs)                              v = Wih2[row * Hs + k];
            else if (k >= H2COL && k < H2COL + Hs)   v = Whh2[row * Hs + (k - H2COL)];
        }
        u16 hh = bfh_(v);
        h[j] = (short)hh;
        l[j] = (short)bfh_(v - bff_(hh));
    }
    FragHL r; r.h = h; r.l = l; return r;
}

// ---- packed weight store: [tid][32 frag slots][8 u16] + fused biases ----
__device__ __align__(16) u16   g_pack[NT * 32 * 8];   // 256 KB
__device__ __align__(16) float g_bias[NT * 4];

__global__ __launch_bounds__(NT) void prep_kernel(
    const float* __restrict__ W_ih1, const float* __restrict__ W_hh1,
    const float* __restrict__ b_ih1, const float* __restrict__ b_hh1,
    const float* __restrict__ W_ih2, const float* __restrict__ W_hh2,
    const float* __restrict__ b_ih2, const float* __restrict__ b_hh2)
{
    const int tid  = threadIdx.x;
    const int lane = tid & 63;
    const int wv   = tid >> 6;
    const int role = wv >> 2;
    const int jg   = wv & 3;
    const int m    = lane & 15;
    const int ch   = lane >> 4;
    const int jrow = jg * 16 + m;
    const bool rv  = jrow < Hs;
    const int nks  = role ? 4 : 2;
    u16* base = &g_pack[tid * 256];

    for (int g = 0; g < 4; ++g) {
        const int row = g * Hs + jrow;
        g_bias[tid * 4 + g] = rv ? (role ? (b_ih2[row] + b_hh2[row])
                                         : (b_ih1[row] + b_hh1[row]))
                                 : 0.f;
        for (int s = 0; s < nks; ++s) {
            FragHL f = role ? mkB2(W_ih2, W_hh2, row, rv, s, ch)
                            : mkB1(W_hh1, W_ih1, row, rv, s, ch);
            *(bf16x8*)(base + (g * (2 * nks) + 2 * s + 0) * 8) = f.h;
            *(bf16x8*)(base + (g * (2 * nks) + 2 * s + 1) * 8) = f.l;
        }
    }
}

// opaque fragment load: value cannot be rematerialized by the compiler
__device__ __forceinline__ bf16x8 ldfrag(const u16* p) {
    i32x4 v = *(const i32x4*)p;
    asm volatile("" : "+v"(v));
    union { i32x4 i; bf16x8 b; } u;
    u.i = v;
    return u.b;
}

#define MFMA_(A, B, C) __builtin_amdgcn_mfma_f32_16x16x32_bf16(A, B, C, 0, 0, 0)

__global__ __launch_bounds__(NT)
void lstm2_kernel(
    const float* __restrict__ x,      // (T, B, 1)
    const float* __restrict__ W_lin,  // (1, 51)
    const float* __restrict__ b_lin,  // (1,)
    float* __restrict__ out)          // (B, T)
{
    __shared__ __align__(16) u16      Ah[2][NBA * SA];
    __shared__ __align__(16) u16      Al[2][NBA * SA];
    __shared__ __align__(16) unsigned xs32[Ts][NB];    // packed (hi,lo) x
    __shared__ __align__(16) float    h2f[2][NB][68];
    __shared__ __align__(16) float    ybuf[NB][Ts];    // 8 KB output buffer
    __shared__ __align__(16) float    wlin_s[64];
    __shared__ float blin_sh;

    const int tid  = threadIdx.x;
    const int lane = tid & 63;
    const int wv   = tid >> 6;         // 0..7
    const int role = wv >> 2;          // 0 = L1, 1 = L2
    const int jg   = wv & 3;
    const int m    = lane & 15;
    const int ch   = lane >> 4;
    const int bg0  = blockIdx.x * NB;
    const int  jrow = jg * 16 + m;     // unit index (valid < 51)
    const bool rv   = jrow < Hs;

    // ---- one-time init: zero / preload (NO staging writes yet) ----
    for (int i = tid; i < Ts * NB; i += NT) {
        int t = i >> 2, b = i & 3;
        float xv = x[t * Bs + bg0 + b];
        u16 hh = bfh_(xv);
        u16 hl = bfh_(xv - bff_(hh));
        xs32[t][b] = (unsigned)hh | ((unsigned)hl << 16);
    }
    for (int i = tid; i < 2 * NBA * SA; i += NT) {
        ((u16*)Ah)[i] = 0;
        ((u16*)Al)[i] = 0;
    }
    for (int i = tid; i < 2 * NB * 68; i += NT) ((float*)h2f)[i] = 0.f;
    if (tid < 64) wlin_s[tid] = (tid < Hs) ? W_lin[tid] : 0.f;
    if (tid == 0) blin_sh = b_lin[0];
    __syncthreads();                   // zero-fill visible first (V7 race fix)

    if (tid < NB) {                    // x[0] into parity 1 (read at it=0)
        unsigned v = xs32[0][tid];
        Ah[1][tid * SA + XCOL] = (u16)v;
        Al[1][tid * SA + XCOL] = (u16)(v >> 16);
    }

    // ---- biases: opaque register load ----
    f32x4 bb4 = *(const f32x4*)&g_bias[tid * 4];
    asm volatile("" : "+v"(bb4));
    const float bbI = bb4.x, bbF = bb4.y, bbG = bb4.z, bbO = bb4.w;

    const u16* pk = &g_pack[tid * 256];

    float cc0 = 0.f, cc1 = 0.f, cc2 = 0.f, cc3 = 0.f;
    __syncthreads();                   // staging + wlin visible

    // hoist W_lin / b_lin into registers (constant across the loop)
    const float wl0 = wlin_s[m],      wl1 = wlin_s[m + 16];
    const float wl2 = wlin_s[m + 32], wl3 = wlin_s[m + 48];
    const float blin_r = blin_sh;

    if (role == 0) {
        // ======================= L1 path =======================
        bf16x8 bI0h = ldfrag(pk + (0*4 + 0)*8), bI0l = ldfrag(pk + (0*4 + 1)*8);
        bf16x8 bI1h = ldfrag(pk + (0*4 + 2)*8), bI1l = ldfrag(pk + (0*4 + 3)*8);
        bf16x8 bF0h = ldfrag(pk + (1*4 + 0)*8), bF0l = ldfrag(pk + (1*4 + 1)*8);
        bf16x8 bF1h = ldfrag(pk + (1*4 + 2)*8), bF1l = ldfrag(pk + (1*4 + 3)*8);
        bf16x8 bG0h = ldfrag(pk + (2*4 + 0)*8), bG0l = ldfrag(pk + (2*4 + 1)*8);
        bf16x8 bG1h = ldfrag(pk + (2*4 + 2)*8), bG1l = ldfrag(pk + (2*4 + 3)*8);
        bf16x8 bO0h = ldfrag(pk + (3*4 + 0)*8), bO0l = ldfrag(pk + (3*4 + 1)*8);
        bf16x8 bO1h = ldfrag(pk + (3*4 + 2)*8), bO1l = ldfrag(pk + (3*4 + 3)*8);

        for (int it = 0; it <= Ts + 1; ++it) {
            const int pR = (it - 1) & 1;
            const int pW = it & 1;
            if (it < Ts) {
                const u16* ph = &Ah[pR][m * SA + ch * 8];
                const u16* pl = &Al[pR][m * SA + ch * 8];
                bf16x8 A0h = *(const bf16x8*)(ph);
                bf16x8 A0l = *(const bf16x8*)(pl);
                bf16x8 A1h = *(const bf16x8*)(ph + 32);
                bf16x8 A1l = *(const bf16x8*)(pl + 32);
                // 3 independent 2-deep chains per gate, merged with adds
                #define L1GATE(OUT, BB, B0h, B0l, B1h, B1l)                    \
                {                                                              \
                    f32x4 p = {BB, BB, BB, BB};                                \
                    f32x4 q = {0.f, 0.f, 0.f, 0.f};                            \
                    f32x4 r = {0.f, 0.f, 0.f, 0.f};                            \
                    p = MFMA_(A0h, B0h, p); p = MFMA_(A1h, B1h, p);            \
                    q = MFMA_(A0l, B0h, q); q = MFMA_(A1l, B1h, q);            \
                    r = MFMA_(A0h, B0l, r); r = MFMA_(A1h, B1l, r);            \
                    OUT = (p + q) + r;                                         \
                }
                f32x4 aI, aF, aG, aO;
                L1GATE(aI, bbI, bI0h, bI0l, bI1h, bI1l)
                L1GATE(aF, bbF, bF0h, bF0l, bF1h, bF1l)
                L1GATE(aG, bbG, bG0h, bG0l, bG1h, bG1l)
                L1GATE(aO, bbO, bO0h, bO0l, bO1h, bO1l)
                #undef L1GATE
                #define E1STEP(RR, CC)                                         \
                {                                                              \
                    float iv = sig_ (aI[RR]);                                  \
                    float fv = sig_ (aF[RR]);                                  \
                    float gv = tanh_(aG[RR]);                                  \
                    float ov = sig_ (aO[RR]);                                  \
                    CC = fmaf(fv, CC, iv * gv);                                \
                    float hv = ov * tanh_(CC);                                 \
                    if (rv && ch == 0) {                                       \
                        const int b = RR;                                      \
                        u16 hh = bfh_(hv);                                     \
                        Ah[pW][b * SA + jrow] = hh;                            \
                        Al[pW][b * SA + jrow] = bfh_(hv - bff_(hh));           \
                    }                                                          \
                }
                E1STEP(0, cc0) E1STEP(1, cc1) E1STEP(2, cc2) E1STEP(3, cc3)
                #undef E1STEP
            }
            // x[it+1] staging into parity pW (wave 0, NB lanes; pre-split)
            if (jg == 0 && lane < NB && (it + 1) < Ts) {
                unsigned v = xs32[it + 1][lane];
                Ah[pW][lane * SA + XCOL] = (u16)v;
                Al[pW][lane * SA + XCOL] = (u16)(v >> 16);
            }
            // y[it-2] = W_lin . h2[it-2] + b -> LDS ybuf; batch = jg
            if (it >= 2) {
                const float* hp = &h2f[it & 1][jg][0];
                float s = wl0 * hp[m] + wl1 * hp[m + 16]
                        + wl2 * hp[m + 32] + wl3 * hp[m + 48];
                s += __shfl_xor(s, 1);
                s += __shfl_xor(s, 2);
                s += __shfl_xor(s, 4);
                s += __shfl_xor(s, 8);
                if (lane == 0) ybuf[jg][it - 2] = s + blin_r;
            }
            __syncthreads();
        }
    } else {
        // ======================= L2 path =======================
        bf16x8 cI0h = ldfrag(pk + (0*8 + 0)*8), cI0l = ldfrag(pk + (0*8 + 1)*8);
        bf16x8 cI1h = ldfrag(pk + (0*8 + 2)*8), cI1l = ldfrag(pk + (0*8 + 3)*8);
        bf16x8 cI2h = ldfrag(pk + (0*8 + 4)*8), cI2l = ldfrag(pk + (0*8 + 5)*8);
        bf16x8 cI3h = ldfrag(pk + (0*8 + 6)*8), cI3l = ldfrag(pk + (0*8 + 7)*8);
        bf16x8 cF0h = ldfrag(pk + (1*8 + 0)*8), cF0l = ldfrag(pk + (1*8 + 1)*8);
        bf16x8 cF1h = ldfrag(pk + (1*8 + 2)*8), cF1l = ldfrag(pk + (1*8 + 3)*8);
        bf16x8 cF2h = ldfrag(pk + (1*8 + 4)*8), cF2l = ldfrag(pk + (1*8 + 5)*8);
        bf16x8 cF3h = ldfrag(pk + (1*8 + 6)*8), cF3l = ldfrag(pk + (1*8 + 7)*8);
        bf16x8 cG0h = ldfrag(pk + (2*8 + 0)*8), cG0l = ldfrag(pk + (2*8 + 1)*8);
        bf16x8 cG1h = ldfrag(pk + (2*8 + 2)*8), cG1l = ldfrag(pk + (2*8 + 3)*8);
        bf16x8 cG2h = ldfrag(pk + (2*8 + 4)*8), cG2l = ldfrag(pk + (2*8 + 5)*8);
        bf16x8 cG3h = ldfrag(pk + (2*8 + 6)*8), cG3l = ldfrag(pk + (2*8 + 7)*8);
        bf16x8 cO0h = ldfrag(pk + (3*8 + 0)*8), cO0l = ldfrag(pk + (3*8 + 1)*8);
        bf16x8 cO1h = ldfrag(pk + (3*8 + 2)*8), cO1l = ldfrag(pk + (3*8 + 3)*8);
        bf16x8 cO2h = ldfrag(pk + (3*8 + 4)*8), cO2l = ldfrag(pk + (3*8 + 5)*8);
        bf16x8 cO3h = ldfrag(pk + (3*8 + 6)*8), cO3l = ldfrag(pk + (3*8 + 7)*8);

        for (int it = 0; it <= Ts + 1; ++it) {
            const int pR = (it - 1) & 1;
            const int pW = it & 1;
            if (it >= 1 && it <= Ts) {
                const u16* ph = &Ah[pR][m * SA + ch * 8];
                const u16* pl = &Al[pR][m * SA + ch * 8];
                bf16x8 A0h = *(const bf16x8*)(ph);
                bf16x8 A0l = *(const bf16x8*)(pl);
                bf16x8 A1h = *(const bf16x8*)(ph + 32);
                bf16x8 A1l = *(const bf16x8*)(pl + 32);
                bf16x8 A2h = *(const bf16x8*)(ph + 64);
                bf16x8 A2l = *(const bf16x8*)(pl + 64);
                bf16x8 A3h = *(const bf16x8*)(ph + 96);
                bf16x8 A3l = *(const bf16x8*)(pl + 96);
                // 2 chains per gate: 8-deep (Bh terms) + 4-deep (Bl term)
                #define L2GATE(OUT, BB, C0h, C0l, C1h, C1l, C2h, C2l, C3h, C3l)\
                {                                                              \
                    f32x4 p = {BB, BB, BB, BB};                                \
                    f32x4 r = {0.f, 0.f, 0.f, 0.f};                            \
                    p = MFMA_(A0h, C0h, p); p = MFMA_(A1h, C1h, p);            \
                    p = MFMA_(A2h, C2h, p); p = MFMA_(A3h, C3h, p);            \
                    p = MFMA_(A0l, C0h, p); p = MFMA_(A1l, C1h, p);            \
                    p = MFMA_(A2l, C2h, p); p = MFMA_(A3l, C3h, p);            \
                    r = MFMA_(A0h, C0l, r); r = MFMA_(A1h, C1l, r);            \
                    r = MFMA_(A2h, C2l, r); r = MFMA_(A3h, C3l, r);            \
                    OUT = p + r;                                               \
                }
                f32x4 aI, aF, aG, aO;
                L2GATE(aI, bbI, cI0h, cI0l, cI1h, cI1l, cI2h, cI2l, cI3h, cI3l)
                L2GATE(aF, bbF, cF0h, cF0l, cF1h, cF1l, cF2h, cF2l, cF3h, cF3l)
                L2GATE(aG, bbG, cG0h, cG0l, cG1h, cG1l, cG2h, cG2l, cG3h, cG3l)
                L2GATE(aO, bbO, cO0h, cO0l, cO1h, cO1l, cO2h, cO2l, cO3h, cO3l)
                #undef L2GATE
                const int pE = (it - 1) & 1;     // h2f parity for h2[it-1]
                #define E2STEP(RR, CC)                                         \
                {                                                              \
                    float iv = sig_ (aI[RR]);                                  \
                    float fv = sig_ (aF[RR]);                                  \
                    float gv = tanh_(aG[RR]);                                  \
                    float ov = sig_ (aO[RR]);                                  \
                    CC = fmaf(fv, CC, iv * gv);                                \
                    float hv = ov * tanh_(CC);                                 \
                    if (rv && ch == 0) {                                       \
                        const int b = RR;                                      \
                        u16 hh = bfh_(hv);                                     \
                        Ah[pW][b * SA + H2COL + jrow] = hh;                    \
                        Al[pW][b * SA + H2COL + jrow] = bfh_(hv - bff_(hh));   \
                        h2f[pE][b][jrow] = hv;                                 \
                    }                                                          \
                }
                E2STEP(0, cc0) E2STEP(1, cc1) E2STEP(2, cc2) E2STEP(3, cc3)
                #undef E2STEP
            }
            __syncthreads();
        }
    }

    // ---- single coalesced flush of the output buffer ----
    __syncthreads();
    for (int i = tid; i < NB * Ts; i += NT) {
        int b = i >> 9, t = i & (Ts - 1);
        out[(bg0 + b) * Ts + t] = ybuf[b][t];
    }
}

extern "C" void kernel_launch(void* const* d_in, const int* in_sizes, int n_in,
                              void* d_out, int out_size, void* d_ws, size_t ws_size,
                              hipStream_t stream) {
    const float* x     = (const float*)d_in[0];
    const float* W_ih1 = (const float*)d_in[1];
    const float* W_hh1 = (const float*)d_in[2];
    const float* b_ih1 = (const float*)d_in[3];
    const float* b_hh1 = (const float*)d_in[4];
    const float* W_ih2 = (const float*)d_in[5];
    const float* W_hh2 = (const float*)d_in[6];
    const float* b_ih2 = (const float*)d_in[7];
    const float* b_hh2 = (const float*)d_in[8];
    const float* W_lin = (const float*)d_in[9];
    const float* b_lin = (const float*)d_in[10];
    float* out = (float*)d_out;

    prep_kernel<<<1, NT, 0, stream>>>(W_ih1, W_hh1, b_ih1, b_hh1,
                                      W_ih2, W_hh2, b_ih2, b_hh2);
    lstm2_kernel<<<Bs / NB, NT, 0, stream>>>(x, W_lin, b_lin, out);
}